// Round 7
// baseline (124.775 us; speedup 1.0000x reference)
//
#include <hip/hip_runtime.h>
#include <hip/hip_bf16.h>

#define K_DIM 16384
#define M_DIM 512
#define N_DIM 2560
#define BM 256
#define BN 160
#define BK 64
#define KSPLIT 8
#define KCH (K_DIM / KSPLIT)   // 2048
#define NK (KCH / BK)          // 32

typedef float f32x4 __attribute__((ext_vector_type(4)));
typedef __bf16 bf16x8 __attribute__((ext_vector_type(8)));

__device__ __forceinline__ unsigned short f2bf(float f){
  union { float f; unsigned u; } v; v.f = f;
  unsigned r = v.u + 0x7FFFu + ((v.u >> 16) & 1u);
  return (unsigned short)(r >> 16);
}
__device__ __forceinline__ unsigned bfpack2(float lo, float hi){
  return (unsigned)f2bf(lo) | ((unsigned)f2bf(hi) << 16);
}

// K1: w_mean[c] = mean_f conv1_w[f][c]; b_mean = mean(conv1_b)
__global__ __launch_bounds__(256)
void prep_kernel(const float* __restrict__ conv1_w, const float* __restrict__ conv1_b,
                 float* __restrict__ w_mean, float* __restrict__ b_mean)
{
  int c = blockIdx.x * 256 + threadIdx.x;
  if (c < K_DIM){
    float s = 0.f;
    #pragma unroll
    for (int f = 0; f < 10; ++f) s += conv1_w[f * K_DIM + c];
    w_mean[c] = s * 0.1f;
  }
  if (blockIdx.x == 0 && threadIdx.x == 0){
    float s = 0.f;
    #pragma unroll
    for (int f = 0; f < 10; ++f) s += conv1_b[f];
    *b_mean = s * 0.1f;
  }
}

// K2: pooled[row] = x[row,:].w_mean + b_mean  AND  xbf[row,:] = bf16(x[row,:])
__global__ __launch_bounds__(256)
void pooled_kernel(const float* __restrict__ X, const float* __restrict__ w_mean,
                   const float* __restrict__ b_mean, float* __restrict__ pooled,
                   unsigned short* __restrict__ xbf)
{
  const int row = blockIdx.x;
  const int tid = threadIdx.x;
  const float* xr = X + (size_t)row * K_DIM;
  unsigned short* xb = xbf + (size_t)row * K_DIM;
  float s = 0.f;
  #pragma unroll 2
  for (int i = 0; i < 8; ++i){
    int idx = (tid + 256 * i) * 8;
    float4 a0 = *(const float4*)(xr + idx);
    float4 a1 = *(const float4*)(xr + idx + 4);
    float4 w0 = *(const float4*)(w_mean + idx);
    float4 w1 = *(const float4*)(w_mean + idx + 4);
    s += a0.x*w0.x + a0.y*w0.y + a0.z*w0.z + a0.w*w0.w
       + a1.x*w1.x + a1.y*w1.y + a1.z*w1.z + a1.w*w1.w;
    uint4 p;
    p.x = bfpack2(a0.x, a0.y); p.y = bfpack2(a0.z, a0.w);
    p.z = bfpack2(a1.x, a1.y); p.w = bfpack2(a1.z, a1.w);
    *(uint4*)(xb + idx) = p;
  }
  #pragma unroll
  for (int off = 32; off; off >>= 1) s += __shfl_down(s, off);
  __shared__ float red[4];
  if ((tid & 63) == 0) red[tid >> 6] = s;
  __syncthreads();
  if (tid == 0) pooled[row] = red[0] + red[1] + red[2] + red[3] + *b_mean;
}

// K3: gates
__global__ __launch_bounds__(512)
void gates_kernel(const float* __restrict__ pooled, const float* __restrict__ fw,
                  const float* __restrict__ fb, const float* __restrict__ aw,
                  float* __restrict__ gates)
{
  __shared__ float ps[512];
  int tid = threadIdx.x;
  ps[tid] = pooled[tid];
  __syncthreads();
  int b = tid >> 5, s = tid & 31;
  float z = fb[s];
  #pragma unroll
  for (int t = 0; t < 32; ++t) z += ps[b * 32 + t] * fw[s * 32 + t];
  float mx = z;
  #pragma unroll
  for (int off = 16; off; off >>= 1) mx = fmaxf(mx, __shfl_xor(mx, off));
  float e = expf(z - mx);
  float sum = e;
  #pragma unroll
  for (int off = 16; off; off >>= 1) sum += __shfl_xor(sum, off);
  float sm = e / sum;
  float relu = z > 0.f ? z : 0.f;
  float sig = 1.f / (1.f + expf(-z));
  gates[tid] = aw[0] * relu + aw[1] * sig + aw[2] * sm;
}

// K4: BM=256 x BN=160, BK=64, KSPLIT=8 -> grid 2*16*8 = 256 (1 block/CU).
// 8 waves 4m x 2n, wave tile 64x80, acc[4][5]. kz=id&7 XCD-pinned.
// Single barrier per K-step with counted s_waitcnt vmcnt(4) (stage for kt+2 stays
// in flight across the barrier; stage(kt+1) -- older than the newest 4 -- is
// guaranteed drained). A: gll 2-ahead, triple-buffered LDS. B: fp32 reg-staged
// 2-deep by waves 0-4, cvt->bf16, double-buffered LDS.
__global__ __launch_bounds__(512, 2)
void gemm_kernel(const unsigned short* __restrict__ Abf, const float* __restrict__ W,
                 float* __restrict__ outp, int mode)
{
  __shared__ __align__(16) char smem[3 * 32768 + 2 * 20480];  // 139264 B

  const int tid  = threadIdx.x;
  const int lane = tid & 63;
  const int wv   = tid >> 6;
  const int wm   = (wv >> 1) * 64;      // 4 m-waves
  const int wn   = (wv & 1) * 80;       // 2 n-waves

  const int id = blockIdx.x;
  const int kz = id & 7;
  const int r  = id >> 3;               // 0..31
  const int m0 = (r & 1) * BM;
  const int n0 = (r >> 1) * BN;
  const int kbase = kz * KCH;

  f32x4 acc[4][5] = {};

  // A gll mapping: chunk u = j*512 + tid -> row = j*64 + (tid>>3), c8 = tid&7.
  // LDS[row][c8] holds A[row][c8 ^ (row&7)]; row&7 == (tid>>3)&7.
  const int arow0 = tid >> 3;
  const int ac8   = (tid & 7) ^ (arow0 & 7);
  const unsigned short* asrc = Abf + (size_t)(m0 + arow0) * K_DIM + ac8 * 8;
  const int adst = tid * 16;

  auto stageA = [&](char* dst, int k0){
    #pragma unroll
    for (int j = 0; j < 4; ++j){
      __builtin_amdgcn_global_load_lds(
        (const __attribute__((address_space(1))) void*)(asrc + (size_t)j * 64 * K_DIM + k0),
        (__attribute__((address_space(3))) void*)(dst + j * 8192 + adst),
        16, 0, 0);
    }
  };

  // B staging: threads 0..319 (waves 0-4): row = tid>>1, half = tid&1 -> 32 fp32.
  const int brow  = tid >> 1;
  const int bhalf = tid & 1;
  const bool bact = (tid < 320);
  const float* bsrc = W + (size_t)(n0 + (bact ? brow : 0)) * K_DIM + kbase + bhalf * 32;
  int boff[4];
  #pragma unroll
  for (int h = 0; h < 4; ++h)
    boff[h] = brow * 128 + ((((bhalf * 4 + h) * 16)) ^ ((brow & 7) << 4));

  auto loadB = [&](int kt, float4* rr){
    if (bact){
      const float* p = bsrc + kt * BK;
      #pragma unroll
      for (int q = 0; q < 8; ++q) rr[q] = *(const float4*)(p + q * 4);
    }
  };
  auto writeB = [&](char* dst, const float4* rr){
    if (bact){
      #pragma unroll
      for (int h = 0; h < 4; ++h){
        uint4 u;
        u.x = bfpack2(rr[2*h].x,   rr[2*h].y);   u.y = bfpack2(rr[2*h].z,   rr[2*h].w);
        u.z = bfpack2(rr[2*h+1].x, rr[2*h+1].y); u.w = bfpack2(rr[2*h+1].z, rr[2*h+1].w);
        *(uint4*)(dst + boff[h]) = u;
      }
    }
  };

  char* Ar = smem;              // A read (kt)
  char* As = smem + 32768;      // A staged (kt+1, in flight/complete)
  char* At = smem + 65536;      // A stage target (kt+2)
  char* Br = smem + 98304;      // B read
  char* Bw = smem + 118784;     // B write

  float4 rbA[8], rbB[8];

  // prologue: B(0)->LDS (drained by its own use-wait), B(1)->rbB, A(0),A(1) staged.
  loadB(0, rbA);
  writeB(Br, rbA);
  loadB(1, rbB);
  stageA(Ar, kbase);
  stageA(As, kbase + BK);
  asm volatile("s_waitcnt vmcnt(4) lgkmcnt(0)" ::: "memory");
  __builtin_amdgcn_s_barrier();

  auto compute = [&](const char* A_, const char* B_){
    #pragma unroll
    for (int kk = 0; kk < 2; ++kk){
      bf16x8 af[4], bfv[5];
      const int kbyte = kk * 64 + (lane >> 4) * 16;
      #pragma unroll
      for (int i = 0; i < 4; ++i){
        int row = wm + i * 16 + (lane & 15);
        af[i] = *(const bf16x8*)(A_ + row * 128 + (kbyte ^ ((row & 7) << 4)));
      }
      #pragma unroll
      for (int j = 0; j < 5; ++j){
        int row = wn + j * 16 + (lane & 15);
        bfv[j] = *(const bf16x8*)(B_ + row * 128 + (kbyte ^ ((row & 7) << 4)));
      }
      #pragma unroll
      for (int i = 0; i < 4; ++i)
        #pragma unroll
        for (int j = 0; j < 5; ++j)
          acc[i][j] = __builtin_amdgcn_mfma_f32_16x16x32_bf16(af[i], bfv[j], acc[i][j], 0, 0, 0);
    }
  };

  #define BODY(KT, RW, RL)                                              \
    do {                                                                \
      if ((KT) + 2 < NK) loadB((KT) + 2, RL);                           \
      if ((KT) + 2 < NK) stageA(At, kbase + ((KT) + 2) * BK);           \
      if ((KT) + 1 < NK) writeB(Bw, RW);                                \
      compute(Ar, Br);                                                  \
      asm volatile("s_waitcnt vmcnt(4) lgkmcnt(0)" ::: "memory");       \
      __builtin_amdgcn_s_barrier();                                     \
      { char* t_ = Ar; Ar = As; As = At; At = t_; }                     \
      { char* t_ = Br; Br = Bw; Bw = t_; }                              \
    } while (0)

  for (int kt = 0; kt < NK; kt += 2){
    BODY(kt, rbB, rbA);
    BODY(kt + 1, rbA, rbB);
  }
  #undef BODY

  if (mode == 0){
    float* P = outp + (size_t)kz * M_DIM * N_DIM;
    #pragma unroll
    for (int i = 0; i < 4; ++i){
      int rbase = m0 + wm + i * 16 + (lane >> 4) * 4;
      #pragma unroll
      for (int j = 0; j < 5; ++j){
        int col = n0 + wn + j * 16 + (lane & 15);
        #pragma unroll
        for (int r2 = 0; r2 < 4; ++r2)
          P[(size_t)(rbase + r2) * N_DIM + col] = acc[i][j][r2];
      }
    }
  } else {
    #pragma unroll
    for (int i = 0; i < 4; ++i){
      int rbase = m0 + wm + i * 16 + (lane >> 4) * 4;
      #pragma unroll
      for (int j = 0; j < 5; ++j){
        int col = n0 + wn + j * 16 + (lane & 15);
        #pragma unroll
        for (int r2 = 0; r2 < 4; ++r2)
          atomicAdd(&outp[(size_t)(rbase + r2) * N_DIM + col], acc[i][j][r2]);
      }
    }
  }
}

// K5a: out[m,n] = gates[m] * (sum_z partial[z,m,n] + bias[n])
__global__ __launch_bounds__(256)
void reduce_kernel(const float* __restrict__ part, const float* __restrict__ gates,
                   const float* __restrict__ bias, float* __restrict__ out, int ksplit)
{
  int i4 = blockIdx.x * 256 + threadIdx.x;
  if (i4 >= M_DIM * N_DIM / 4) return;
  size_t off = (size_t)i4 * 4;
  int m = (int)(off / N_DIM);
  int n = (int)(off % N_DIM);
  float sx = 0.f, sy = 0.f, sz = 0.f, sw = 0.f;
  for (int z = 0; z < ksplit; ++z){
    float4 p = *(const float4*)(part + (size_t)z * M_DIM * N_DIM + off);
    sx += p.x; sy += p.y; sz += p.z; sw += p.w;
  }
  float4 bv = *(const float4*)(bias + n);
  float g = gates[m];
  float4 o;
  o.x = g * (sx + bv.x); o.y = g * (sy + bv.y);
  o.z = g * (sz + bv.z); o.w = g * (sw + bv.w);
  *(float4*)(out + off) = o;
}

// K5b: finalize after atomic accumulation
__global__ __launch_bounds__(256)
void finalize_kernel(float* __restrict__ out, const float* __restrict__ gates,
                     const float* __restrict__ bias)
{
  int i4 = blockIdx.x * 256 + threadIdx.x;
  if (i4 >= M_DIM * N_DIM / 4) return;
  size_t off = (size_t)i4 * 4;
  int m = (int)(off / N_DIM);
  int n = (int)(off % N_DIM);
  float4 o = *(const float4*)(out + off);
  float4 bv = *(const float4*)(bias + n);
  float g = gates[m];
  o.x = g * (o.x + bv.x); o.y = g * (o.y + bv.y);
  o.z = g * (o.z + bv.z); o.w = g * (o.w + bv.w);
  *(float4*)(out + off) = o;
}

extern "C" void kernel_launch(void* const* d_in, const int* in_sizes, int n_in,
                              void* d_out, int out_size, void* d_ws, size_t ws_size,
                              hipStream_t stream)
{
  const float* input   = (const float*)d_in[0];
  const float* aw      = (const float*)d_in[2];
  const float* conv1_w = (const float*)d_in[3];
  const float* conv1_b = (const float*)d_in[4];
  const float* G3_w    = (const float*)d_in[5];
  const float* G3_b    = (const float*)d_in[6];
  const float* ffnn1_w = (const float*)d_in[7];
  const float* ffnn1_b = (const float*)d_in[8];
  float* out = (float*)d_out;

  float* wsf    = (float*)d_ws;
  float* w_mean = wsf;               // 16384 f
  float* pooled = wsf + 16384;       // 512 f
  float* gates  = wsf + 16896;       // 512 f
  float* b_mean = wsf + 17408;       // 64 f pad
  unsigned short* xbf = (unsigned short*)(wsf + 17472);        // 512*16384 bf16 = 16MB
  float* partial = wsf + 17472 + (size_t)M_DIM * K_DIM / 2;    // 8 * 512*2560 f

  const size_t need_det = ((size_t)17472 + (size_t)M_DIM * K_DIM / 2
                           + (size_t)KSPLIT * M_DIM * N_DIM) * 4;   // ~58.8MB

  prep_kernel<<<64, 256, 0, stream>>>(conv1_w, conv1_b, w_mean, b_mean);
  pooled_kernel<<<512, 256, 0, stream>>>(input, w_mean, b_mean, pooled, xbf);
  gates_kernel<<<1, 512, 0, stream>>>(pooled, ffnn1_w, ffnn1_b, aw, gates);

  const int n4 = M_DIM * N_DIM / 4;
  const int grid = (M_DIM / BM) * (N_DIM / BN) * KSPLIT;   // 2*16*8 = 256
  if (ws_size >= need_det){
    gemm_kernel<<<grid, 512, 0, stream>>>(xbf, G3_w, partial, 0);
    reduce_kernel<<<(n4 + 255) / 256, 256, 0, stream>>>(partial, gates, G3_b, out, KSPLIT);
  } else {
    hipMemsetAsync(d_out, 0, (size_t)out_size * sizeof(float), stream);
    gemm_kernel<<<grid, 512, 0, stream>>>(xbf, G3_w, out, 2);
    finalize_kernel<<<(n4 + 255) / 256, 256, 0, stream>>>(out, gates, G3_b);
  }
}